// Round 4
// baseline (241.736 us; speedup 1.0000x reference)
//
#include <hip/hip_runtime.h>

// ShortConvolution: depthwise causal conv1d (K=4) + SiLU
// x: (B=4, T=4096, D=2048) fp32, weight: (D, K) fp32, out: (B, T, D) fp32
// y[b,t,d] = silu( sum_k w[d,k] * x[b, t-3+k, d] )   (x[t<0] = 0)
//
// R6 = R5 (long-strip rolling pipeline) with CORRECTED vmcnt accounting.
// R5 bug: stores also increment vmcnt and occupy FIFO slots; counting only
// loads made waits too weak from iter 9 on (silent data corruption).
//
// Structure rationale (from R3/R4 post-mortems, both neutral at 80us /
// 2.8 TB/s): per-wave concurrency and store path are exonerated; the
// limiter is the bursty one-shot 8-row block shape (read-storm /
// write-storm, 37.5% halo demand, launch+drain churn). The 6.29 TB/s copy
// bench is long-lived waves with steady interleaved 1:1 read/write.
// Converge to that: each block owns a 32-step strip of (batch, D-half);
// per-lane 16-slot register ring; steady state = prefetch(t+8) ->
// counted vmcnt -> 4 FMA + SiLU -> store(t). Halo 37.5% -> 9%. Mapping
// bid = c*8 + (b*2+ds) pins each (b,ds) slab to one XCD, strips
// sequential in c -> halos L2-local, contiguous slab streaming.
// 1024 blocks x 4 waves = 16 waves/CU, single occupancy round.
//
// vmcnt FIFO accounting (loads AND stores, in-order retire):
//   prologue: 4 q-loads + 11 row loads (rows -3..7)     -> ops 1..15
//   iter j:   prefetch(row j+8) at pos 16+2j (j<=23), store(j) at 17+2j
//   at VWAIT of iter i: issued = 16+2i (i<=23) | 39+i (i>=24)
//   needed: row i at pos 8+i (i<=7, prologue) | 2i (i>=8, prefetched)
//   => N = 8+i (i=0..7) | 16 (i=8..23) | 39-i (i=24..31)
// Stores may sink below the next prefetch (no barrier between them);
// that only lowers the needed row's position -> N above stays safe.

#define B_DIM 4
#define T_DIM 4096
#define D_DIM 2048
#define K_DIM 4
#define TC    32               // timesteps per block strip
#define PF    8                // prefetch depth (rows ahead)
#define ROWF4 (D_DIM / 4)

typedef float f4_t __attribute__((ext_vector_type(4)));

#define GLOAD(dst, voff, sbase) \
    asm volatile("global_load_dwordx4 %0, %1, %2" : "=&v"(dst) : "v"(voff), "s"(sbase))
#define GLOADO(dst, voff, sbase, o) \
    asm volatile("global_load_dwordx4 %0, %1, %2 offset:" #o : "=&v"(dst) : "v"(voff), "s"(sbase))
#define VWAIT(n) \
    asm volatile("s_waitcnt vmcnt(" #n ")" ::: "memory"); \
    __builtin_amdgcn_sched_barrier(0)

__global__ __launch_bounds__(256, 4) void shortconv_silu_kernel(
    const float* __restrict__ x,
    const float* __restrict__ w,
    float* __restrict__ out)
{
    // bid = c*8 + b*2 + ds : XCD(bid%8) owns one (b,ds) pair, strips
    // sequential in c on the same XCD.
    const int bid = blockIdx.x;
    const int c   = bid >> 3;                 // 0..127
    const int b   = (bid >> 1) & 3;
    const int ds  = bid & 1;                  // which half of D
    const int t0  = c * TC;
    const int tid = threadIdx.x;              // 0..255
    const int d4  = ds * 256 + tid;           // f4 index over D (0..511)

    const float* xs = x   + (size_t)b * T_DIM * D_DIM + (size_t)ds * 1024;
    float*       os = out + (size_t)b * T_DIM * D_DIM + (size_t)ds * 1024;
    f4_t* ov = (f4_t*)os + tid;

    const unsigned lane_off = (unsigned)tid * 16u;   // within a (half-)row
    const unsigned w_off    = (unsigned)d4 * 64u;    // 4 ch x 4 taps x 4B

    f4_t q0, q1, q2, q3;
    f4_t r0, r1, r2, r3, r4, r5, r6, r7, r8, r9, r10, r11, r12, r13, r14, r15;

    // ---- Prologue: 4 weight loads + rows -3..7 (11 loads), FIFO order ----
    GLOAD (q0, w_off, w);
    GLOADO(q1, w_off, w, 16);
    GLOADO(q2, w_off, w, 32);
    GLOADO(q3, w_off, w, 48);

    // Halo rows (slots 13,14,15). For c==0 load row 0 (valid addr), then
    // overwrite with zeros after the first wait — keeps ONE vmcnt schedule.
    const int tm3 = (c == 0) ? 0 : t0 - 3;
    const int tm2 = (c == 0) ? 0 : t0 - 2;
    const int tm1 = (c == 0) ? 0 : t0 - 1;
    GLOAD(r13, lane_off, xs + (size_t)tm3 * D_DIM);
    GLOAD(r14, lane_off, xs + (size_t)tm2 * D_DIM);
    GLOAD(r15, lane_off, xs + (size_t)tm1 * D_DIM);
    GLOAD(r0,  lane_off, xs + (size_t)(t0 + 0) * D_DIM);
    GLOAD(r1,  lane_off, xs + (size_t)(t0 + 1) * D_DIM);
    GLOAD(r2,  lane_off, xs + (size_t)(t0 + 2) * D_DIM);
    GLOAD(r3,  lane_off, xs + (size_t)(t0 + 3) * D_DIM);
    GLOAD(r4,  lane_off, xs + (size_t)(t0 + 4) * D_DIM);
    GLOAD(r5,  lane_off, xs + (size_t)(t0 + 5) * D_DIM);
    GLOAD(r6,  lane_off, xs + (size_t)(t0 + 6) * D_DIM);
    GLOAD(r7,  lane_off, xs + (size_t)(t0 + 7) * D_DIM);

#define BODY(i, AV, BV, CV, DV)                                           \
    do {                                                                  \
        f4_t y;                                                           \
        y.x = q0.x*(AV).x + q0.y*(BV).x + q0.z*(CV).x + q0.w*(DV).x;      \
        y.y = q1.x*(AV).y + q1.y*(BV).y + q1.z*(CV).y + q1.w*(DV).y;      \
        y.z = q2.x*(AV).z + q2.y*(BV).z + q2.z*(CV).z + q2.w*(DV).z;      \
        y.w = q3.x*(AV).w + q3.y*(BV).w + q3.z*(CV).w + q3.w*(DV).w;      \
        y.x = y.x / (1.f + __expf(-y.x));                                 \
        y.y = y.y / (1.f + __expf(-y.y));                                 \
        y.z = y.z / (1.f + __expf(-y.z));                                 \
        y.w = y.w / (1.f + __expf(-y.w));                                 \
        ov[(size_t)(t0 + (i)) * ROWF4] = y;                               \
    } while (0)

#define STEP_PF(i, N, AV, BV, CV, DV, RP)                                 \
    GLOAD(RP, lane_off, xs + (size_t)(t0 + (i) + PF) * D_DIM);            \
    VWAIT(N);                                                             \
    BODY(i, AV, BV, CV, DV)

#define STEP_NP(i, N, AV, BV, CV, DV)                                     \
    VWAIT(N);                                                             \
    BODY(i, AV, BV, CV, DV)

    // ---- Iter 0 (manual: zero-fix halo slots after first wait) ----
    GLOAD(r8, lane_off, xs + (size_t)(t0 + 8) * D_DIM);
    VWAIT(8);
    if (c == 0) { r13 = (f4_t)0.f; r14 = (f4_t)0.f; r15 = (f4_t)0.f; }
    BODY(0, r13, r14, r15, r0);

    // Warm-up: N = 8+i
    STEP_PF( 1,  9, r14, r15, r0,  r1,  r9 );
    STEP_PF( 2, 10, r15, r0,  r1,  r2,  r10);
    STEP_PF( 3, 11, r0,  r1,  r2,  r3,  r11);
    STEP_PF( 4, 12, r1,  r2,  r3,  r4,  r12);
    STEP_PF( 5, 13, r2,  r3,  r4,  r5,  r13);
    STEP_PF( 6, 14, r3,  r4,  r5,  r6,  r14);
    STEP_PF( 7, 15, r4,  r5,  r6,  r7,  r15);
    // Steady state: N = 16 (each iter issues prefetch+store, consumes one row)
    STEP_PF( 8, 16, r5,  r6,  r7,  r8,  r0 );
    STEP_PF( 9, 16, r6,  r7,  r8,  r9,  r1 );
    STEP_PF(10, 16, r7,  r8,  r9,  r10, r2 );
    STEP_PF(11, 16, r8,  r9,  r10, r11, r3 );
    STEP_PF(12, 16, r9,  r10, r11, r12, r4 );
    STEP_PF(13, 16, r10, r11, r12, r13, r5 );
    STEP_PF(14, 16, r11, r12, r13, r14, r6 );
    STEP_PF(15, 16, r12, r13, r14, r15, r7 );
    STEP_PF(16, 16, r13, r14, r15, r0,  r8 );
    STEP_PF(17, 16, r14, r15, r0,  r1,  r9 );
    STEP_PF(18, 16, r15, r0,  r1,  r2,  r10);
    STEP_PF(19, 16, r0,  r1,  r2,  r3,  r11);
    STEP_PF(20, 16, r1,  r2,  r3,  r4,  r12);
    STEP_PF(21, 16, r2,  r3,  r4,  r5,  r13);
    STEP_PF(22, 16, r3,  r4,  r5,  r6,  r14);
    STEP_PF(23, 16, r4,  r5,  r6,  r7,  r15);
    // Drain: N = 39 - i
    STEP_NP(24, 15, r5,  r6,  r7,  r8 );
    STEP_NP(25, 14, r6,  r7,  r8,  r9 );
    STEP_NP(26, 13, r7,  r8,  r9,  r10);
    STEP_NP(27, 12, r8,  r9,  r10, r11);
    STEP_NP(28, 11, r9,  r10, r11, r12);
    STEP_NP(29, 10, r10, r11, r12, r13);
    STEP_NP(30,  9, r11, r12, r13, r14);
    STEP_NP(31,  8, r12, r13, r14, r15);

#undef STEP_NP
#undef STEP_PF
#undef BODY
}

extern "C" void kernel_launch(void* const* d_in, const int* in_sizes, int n_in,
                              void* d_out, int out_size, void* d_ws, size_t ws_size,
                              hipStream_t stream) {
    const float* x = (const float*)d_in[0];
    const float* w = (const float*)d_in[1];
    float* out = (float*)d_out;

    const int n_strips = T_DIM / TC;                 // 128
    dim3 grid(n_strips * B_DIM * 2);                 // 1024 blocks
    dim3 block(256);                                 // 4 waves, half of D
    shortconv_silu_kernel<<<grid, block, 0, stream>>>(x, w, out);
}

// Round 5
// 231.048 us; speedup vs baseline: 1.0463x; 1.0463x over previous
//
#include <hip/hip_runtime.h>

// ShortConvolution: depthwise causal conv1d (K=4) + SiLU
// x: (B=4, T=4096, D=2048) fp32, weight: (D, K) fp32, out: (B, T, D) fp32
// y[b,t,d] = silu( sum_k w[d,k] * x[b, t-3+k, d] )   (x[t<0] = 0)
//
// R7: Five structures (R2..R6: one-shot/strip-pipeline, NT/WB stores,
// forced batch, 256/512t, 1024/2048 blocks) ALL land at 80-83us,
// 2.5-2.8 TB/s, while pure-write fills in the same trace do 6.6 TB/s at
// 9% occupancy. Structure- and occupancy-invariance => per-CU read-path
// service cap (L1/TCP miss-tracking): reads at ~900cy HBM latency with
// O(16-32) outstanding lines/CU cap chip-wide reads at ~2-3 TB/s.
// Writes drain at fill rate (~20us of our 83); read side is 1.6 TB/s.
// Our kernel gains NOTHING from L1 (each x line read once per block;
// halo sharing is cross-CU), so bypass L1 on row loads with the sc0
// scope flag -> miss tracking moves to the deeper TA/L2 queue.
// Single change vs R4: "sc0" on the 11 row loads. Weights stay cached.
//
// vmcnt bookkeeping (FIFO, loads+stores): prologue = 4 q + 11 rows =
// ops 1..15; stores are ops >=16. At ITER(i) wait, issued = 15+i;
// vmcnt(7) forces retire of ops 1..8+i = 4q + rows r0..r(i+3) — exactly
// what BODY(i) needs; stores never sit in the needed prefix. Constant 7.

#define B_DIM 4
#define T_DIM 4096
#define D_DIM 2048
#define K_DIM 4
#define TC    8                // timesteps per block

typedef float f4_t __attribute__((ext_vector_type(4)));

// Row loads: sc0 = bypass CU-local L1 (serve from L2/MALL path).
#define GLOADX(dst, voff, sbase) \
    asm volatile("global_load_dwordx4 %0, %1, %2 sc0" : "=&v"(dst) : "v"(voff), "s"(sbase))
// Weight loads: default caching.
#define GLOAD(dst, voff, sbase) \
    asm volatile("global_load_dwordx4 %0, %1, %2" : "=&v"(dst) : "v"(voff), "s"(sbase))
#define GLOADO(dst, voff, sbase, o) \
    asm volatile("global_load_dwordx4 %0, %1, %2 offset:" #o : "=&v"(dst) : "v"(voff), "s"(sbase))

__global__ __launch_bounds__(512) void shortconv_silu_kernel(
    const float* __restrict__ x,
    const float* __restrict__ w,
    float* __restrict__ out)
{
    const int n_chunks = T_DIM / TC;          // 512
    const int b  = blockIdx.x / n_chunks;
    const int c  = blockIdx.x % n_chunks;
    const int t0 = c * TC;
    const int d4 = threadIdx.x;               // float4 index over D
    const int d0 = d4 * 4;

    const float* xb = x   + (size_t)b * T_DIM * D_DIM;
    float*       ob = out + (size_t)b * T_DIM * D_DIM;
    const int rowstride = D_DIM / 4;          // float4 elements per time row
    f4_t* ov = (f4_t*)ob + d4;

    // Per-lane byte offsets (row base goes in SGPRs: block-uniform).
    const unsigned lane_off = (unsigned)d0 * 4u;            // within a time row
    const unsigned w_off    = (unsigned)d0 * (K_DIM * 4u);  // into weight table

    f4_t q0, q1, q2, q3;
    f4_t r0, r1, r2, r3, r4, r5, r6, r7, r8, r9, r10;

    // ---- Issue ALL loads back-to-back. Weights first (L2-hot). ----
    GLOAD (q0, w_off, w);
    GLOADO(q1, w_off, w, 16);
    GLOADO(q2, w_off, w, 32);
    GLOADO(q3, w_off, w, 48);

    if (c == 0) {
        r0 = (f4_t)0.f; r1 = (f4_t)0.f; r2 = (f4_t)0.f;
        GLOADX(r3,  lane_off, xb + (size_t)(t0 + 0) * D_DIM);
        GLOADX(r4,  lane_off, xb + (size_t)(t0 + 1) * D_DIM);
        GLOADX(r5,  lane_off, xb + (size_t)(t0 + 2) * D_DIM);
        GLOADX(r6,  lane_off, xb + (size_t)(t0 + 3) * D_DIM);
        GLOADX(r7,  lane_off, xb + (size_t)(t0 + 4) * D_DIM);
        GLOADX(r8,  lane_off, xb + (size_t)(t0 + 5) * D_DIM);
        GLOADX(r9,  lane_off, xb + (size_t)(t0 + 6) * D_DIM);
        GLOADX(r10, lane_off, xb + (size_t)(t0 + 7) * D_DIM);
    } else {
        GLOADX(r0,  lane_off, xb + (size_t)(t0 - 3) * D_DIM);
        GLOADX(r1,  lane_off, xb + (size_t)(t0 - 2) * D_DIM);
        GLOADX(r2,  lane_off, xb + (size_t)(t0 - 1) * D_DIM);
        GLOADX(r3,  lane_off, xb + (size_t)(t0 + 0) * D_DIM);
        GLOADX(r4,  lane_off, xb + (size_t)(t0 + 1) * D_DIM);
        GLOADX(r5,  lane_off, xb + (size_t)(t0 + 2) * D_DIM);
        GLOADX(r6,  lane_off, xb + (size_t)(t0 + 3) * D_DIM);
        GLOADX(r7,  lane_off, xb + (size_t)(t0 + 4) * D_DIM);
        GLOADX(r8,  lane_off, xb + (size_t)(t0 + 5) * D_DIM);
        GLOADX(r9,  lane_off, xb + (size_t)(t0 + 6) * D_DIM);
        GLOADX(r10, lane_off, xb + (size_t)(t0 + 7) * D_DIM);
    }

    // ---- Compute + store, one row per iteration, constant FIFO wait. ----
#define ITER(i, A, Bv, Cv, Dv)                                            \
    do {                                                                  \
        asm volatile("s_waitcnt vmcnt(7)" ::: "memory");                  \
        __builtin_amdgcn_sched_barrier(0);                                \
        f4_t y;                                                           \
        y.x = q0.x*(A).x + q0.y*(Bv).x + q0.z*(Cv).x + q0.w*(Dv).x;       \
        y.y = q1.x*(A).y + q1.y*(Bv).y + q1.z*(Cv).y + q1.w*(Dv).y;       \
        y.z = q2.x*(A).z + q2.y*(Bv).z + q2.z*(Cv).z + q2.w*(Dv).z;       \
        y.w = q3.x*(A).w + q3.y*(Bv).w + q3.z*(Cv).w + q3.w*(Dv).w;       \
        y.x = y.x / (1.f + __expf(-y.x));                                 \
        y.y = y.y / (1.f + __expf(-y.y));                                 \
        y.z = y.z / (1.f + __expf(-y.z));                                 \
        y.w = y.w / (1.f + __expf(-y.w));                                 \
        ov[(size_t)(t0 + (i)) * rowstride] = y;                           \
    } while (0)

    ITER(0, r0, r1, r2, r3);
    ITER(1, r1, r2, r3, r4);
    ITER(2, r2, r3, r4, r5);
    ITER(3, r3, r4, r5, r6);
    ITER(4, r4, r5, r6, r7);
    ITER(5, r5, r6, r7, r8);
    ITER(6, r6, r7, r8, r9);
    ITER(7, r7, r8, r9, r10);
#undef ITER
}

extern "C" void kernel_launch(void* const* d_in, const int* in_sizes, int n_in,
                              void* d_out, int out_size, void* d_ws, size_t ws_size,
                              hipStream_t stream) {
    const float* x = (const float*)d_in[0];
    const float* w = (const float*)d_in[1];
    float* out = (float*)d_out;

    const int n_chunks = T_DIM / TC;            // 512
    dim3 grid(B_DIM * n_chunks);                // 2048 blocks
    dim3 block(D_DIM / 4);                      // 512 threads
    shortconv_silu_kernel<<<grid, block, 0, stream>>>(x, w, out);
}

// Round 6
// 229.959 us; speedup vs baseline: 1.0512x; 1.0047x over previous
//
#include <hip/hip_runtime.h>

// ShortConvolution: depthwise causal conv1d (K=4) + SiLU
// x: (B=4, T=4096, D=2048) fp32, weight: (D, K) fp32, out: (B, T, D) fp32
// y[b,t,d] = silu( sum_k w[d,k] * x[b, t-3+k, d] )   (x[t<0] = 0)
//
// R8: probe the LAST untried read path. Six structural variants (R2..R7:
// one-shot / strip-pipeline, NT / WB stores, forced 11-deep batch, sc0
// L1-bypass, 3 grid shapes) ALL land at 80-83 us (2.5-2.8 TB/s), while
// pure-write fills in the same trace hit 6.6 TB/s at 9% occupancy, and
// R6 showed LOWER HBM fetch (more L3 hits) is not faster -> not
// HBM-traffic-bound. Occupancy- and structure-invariance point at a cap
// on serviced outstanding reads per CU on the VGPR-return path.
// global_load_lds is the one read mechanism with a different completion
// structure (DMA into LDS, no VGPR landing). If the cap is in the
// return/tracking queue, this lifts it; if neutral, every read path is
// exhausted and ~3.3 TB/s logical R+W is this op's machine floor.
//
// Structure: 256-thread block owns (b, 8-step chunk, D-half). Stage 11
// half-rows (44 KB LDS, 3 blocks/CU) via global_load_lds width=16:
// wave w stages columns w*64..w*64+63 of every row (lds dest = uniform
// base + lane*16). Compute lane reads ONLY column tid = staged by its
// own wave -> no __syncthreads needed; s_waitcnt vmcnt(0) orders
// DMA-completion before ds_read within the wave (sched_barrier pins it,
// rule #18). c==0 halo rows are ds_write zeros (disjoint slots, compiler
// orders ds_write->ds_read via lgkmcnt).

#define B_DIM 4
#define T_DIM 4096
#define D_DIM 2048
#define K_DIM 4
#define TC    8                 // timesteps per block
#define HALF  (D_DIM / 2)       // 1024 floats per half-row
#define NROW  (TC + 3)          // 11 staged rows
#define ROWF4 (D_DIM / 4)       // f4 elements per full row

typedef float f4_t __attribute__((ext_vector_type(4)));

__device__ __forceinline__ void stage16(const float* g, f4_t* l) {
    __builtin_amdgcn_global_load_lds(
        (const __attribute__((address_space(1))) void*)g,
        (__attribute__((address_space(3))) void*)l,
        16 /*bytes, literal*/, 0 /*offset*/, 0 /*aux*/);
}

__global__ __launch_bounds__(256) void shortconv_silu_kernel(
    const float* __restrict__ x,
    const float* __restrict__ w,
    float* __restrict__ out)
{
    __shared__ f4_t smem[NROW][256];

    const int n_chunks = T_DIM / TC;          // 512
    const int bid = blockIdx.x;
    const int ds  = bid & 1;                  // D half
    const int bc  = bid >> 1;
    const int b   = bc / n_chunks;
    const int c   = bc % n_chunks;
    const int t0  = c * TC;
    const int tid = threadIdx.x;              // 0..255
    const int d4  = ds * 256 + tid;           // f4 index over D
    const int d0  = d4 * 4;

    const float* xs = x   + (size_t)b * T_DIM * D_DIM + (size_t)ds * HALF;
    float*       os = out + (size_t)b * T_DIM * D_DIM + (size_t)ds * HALF;
    f4_t* ov = (f4_t*)os + tid;

    const int wq = tid & 192;                 // wave-uniform LDS column base

    // Per-thread weights: 4 channels x 4 taps (row-major (D,K)) — plain
    // loads, compiler manages their waits (it tracks the builtin's vmcnt).
    const f4_t q0 = *(const f4_t*)(w + (size_t)(d0 + 0) * K_DIM);
    const f4_t q1 = *(const f4_t*)(w + (size_t)(d0 + 1) * K_DIM);
    const f4_t q2 = *(const f4_t*)(w + (size_t)(d0 + 2) * K_DIM);
    const f4_t q3 = *(const f4_t*)(w + (size_t)(d0 + 3) * K_DIM);

    // ---- Stage rows into LDS via DMA path ----
#define STAGE(slot, trow) \
    stage16(xs + (size_t)(trow) * D_DIM + (size_t)tid * 4, &smem[slot][wq])

    if (c != 0) {
        STAGE(0, t0 - 3);
        STAGE(1, t0 - 2);
        STAGE(2, t0 - 1);
    } else {
        smem[0][tid] = (f4_t)0.f;
        smem[1][tid] = (f4_t)0.f;
        smem[2][tid] = (f4_t)0.f;
    }
#pragma unroll
    for (int i = 3; i < NROW; ++i) {
        STAGE(i, t0 + i - 3);
    }
#undef STAGE

    // DMA completion -> LDS visible to this wave. No __syncthreads: each
    // lane reads only column tid, staged by its own wave.
    asm volatile("s_waitcnt vmcnt(0)" ::: "memory");
    __builtin_amdgcn_sched_barrier(0);

    // ---- Compute + store: rolling 4-row window from LDS ----
    f4_t A  = smem[0][tid];
    f4_t Bv = smem[1][tid];
    f4_t Cv = smem[2][tid];
#pragma unroll
    for (int i = 0; i < TC; ++i) {
        const f4_t Dv = smem[i + 3][tid];
        f4_t y;
        y.x = q0.x*A.x + q0.y*Bv.x + q0.z*Cv.x + q0.w*Dv.x;
        y.y = q1.x*A.y + q1.y*Bv.y + q1.z*Cv.y + q1.w*Dv.y;
        y.z = q2.x*A.z + q2.y*Bv.z + q2.z*Cv.z + q2.w*Dv.z;
        y.w = q3.x*A.w + q3.y*Bv.w + q3.z*Cv.w + q3.w*Dv.w;

        y.x = y.x / (1.f + __expf(-y.x));
        y.y = y.y / (1.f + __expf(-y.y));
        y.z = y.z / (1.f + __expf(-y.z));
        y.w = y.w / (1.f + __expf(-y.w));

        ov[(size_t)(t0 + i) * ROWF4] = y;

        A = Bv; Bv = Cv; Cv = Dv;
    }
}

extern "C" void kernel_launch(void* const* d_in, const int* in_sizes, int n_in,
                              void* d_out, int out_size, void* d_ws, size_t ws_size,
                              hipStream_t stream) {
    const float* x = (const float*)d_in[0];
    const float* w = (const float*)d_in[1];
    float* out = (float*)d_out;

    const int n_chunks = T_DIM / TC;            // 512
    dim3 grid(B_DIM * n_chunks * 2);            // 4096 blocks (D split in halves)
    dim3 block(256);
    shortconv_silu_kernel<<<grid, block, 0, stream>>>(x, w, out);
}